// Round 6
// baseline (276.857 us; speedup 1.0000x reference)
//
#include <hip/hip_runtime.h>

#define DD 128
#define BIN_CH 2048  // edges staged per bin block

typedef __attribute__((ext_vector_type(8))) short short8;
typedef __attribute__((ext_vector_type(4))) float f32x4;

__device__ __forceinline__ unsigned short f2bf(float x) {
  unsigned int b = __float_as_uint(x);
  b += 0x7fffu + ((b >> 16) & 1u);
  return (unsigned short)(b >> 16);
}

__device__ __forceinline__ unsigned int cvt_pk_bf16(float lo, float hi) {
  unsigned int d;
  asm("v_cvt_pk_bf16_f32 %0, %1, %2" : "=v"(d) : "v"(lo), "v"(hi));
  return d;
}

// ============== CSR build, bucketed (bucket = dst >> 8, <=256 buckets) ==============
__global__ __launch_bounds__(256) void bhist_kernel(const int* __restrict__ dst,
                                                    int* __restrict__ cnt, int E, int NB) {
  __shared__ int lh[256];
  const int t = threadIdx.x;
  lh[t] = 0;
  __syncthreads();
  const int e4 = E >> 2;
  const int4* d4 = (const int4*)dst;
  for (int i = blockIdx.x * 256 + t; i < e4; i += gridDim.x * 256) {
    int4 v = d4[i];
    atomicAdd(&lh[v.x >> 8], 1);
    atomicAdd(&lh[v.y >> 8], 1);
    atomicAdd(&lh[v.z >> 8], 1);
    atomicAdd(&lh[v.w >> 8], 1);
  }
  if (blockIdx.x == 0) {
    for (int i = (e4 << 2) + t; i < E; i += 256) atomicAdd(&lh[dst[i] >> 8], 1);
  }
  __syncthreads();
  if (t < NB && lh[t]) atomicAdd(&cnt[t], lh[t]);
}

__global__ __launch_bounds__(256) void bscan_kernel(const int* __restrict__ cnt,
                                                    int* __restrict__ bucket_base,
                                                    int* __restrict__ cursor,
                                                    int* __restrict__ offs, int NB, int N) {
  __shared__ int s[256];
  const int t = threadIdx.x;
  int v = (t < NB) ? cnt[t] : 0;
  s[t] = v;
  __syncthreads();
#pragma unroll
  for (int o = 1; o < 256; o <<= 1) {
    int u = (t >= o) ? s[t - o] : 0;
    __syncthreads();
    s[t] += u;
    __syncthreads();
  }
  if (t < NB) {
    bucket_base[t] = s[t] - v;
    cursor[t] = s[t] - v;
  }
  if (t == 255) {
    bucket_base[NB] = s[255];
    offs[N] = s[255];
  }
}

__global__ __launch_bounds__(256) void bin_kernel(const int* __restrict__ src,
                                                  const int* __restrict__ dst,
                                                  int* __restrict__ cursor,
                                                  unsigned int* __restrict__ binned,
                                                  int E, int NB) {
  __shared__ int lcount[256], lbase[256], lcur[256], lgbase[256], sscan[256];
  __shared__ unsigned int stage[BIN_CH];
  const int t = threadIdx.x;
  const int cb = blockIdx.x * BIN_CH;
  lcount[t] = 0;
  __syncthreads();

  int sv[BIN_CH / 256], dv[BIN_CH / 256];
#pragma unroll
  for (int i = 0; i < BIN_CH / 256; ++i) {
    const int idx = cb + i * 256 + t;
    if (idx < E) {
      sv[i] = src[idx];
      dv[i] = dst[idx];
      atomicAdd(&lcount[dv[i] >> 8], 1);
    } else {
      sv[i] = -1;
    }
  }
  __syncthreads();
  sscan[t] = lcount[t];
  __syncthreads();
#pragma unroll
  for (int o = 1; o < 256; o <<= 1) {
    int u = (t >= o) ? sscan[t - o] : 0;
    __syncthreads();
    sscan[t] += u;
    __syncthreads();
  }
  lbase[t] = sscan[t] - lcount[t];
  lcur[t] = lbase[t];
  __syncthreads();
#pragma unroll
  for (int i = 0; i < BIN_CH / 256; ++i) {
    if (sv[i] >= 0) {
      const int b = dv[i] >> 8;
      const int pos = atomicAdd(&lcur[b], 1);
      stage[pos] = (unsigned)sv[i] | ((unsigned)(dv[i] & 255) << 16) | ((unsigned)b << 24);
    }
  }
  __syncthreads();
  if (t < NB && lcount[t]) lgbase[t] = atomicAdd(&cursor[t], lcount[t]);
  __syncthreads();
  const int total = (cb + BIN_CH <= E) ? BIN_CH : (E - cb);
  for (int idx = t; idx < total; idx += 256) {
    const unsigned int rec = stage[idx];
    const int b = rec >> 24;
    binned[lgbase[b] + (idx - lbase[b])] = rec;
  }
}

__global__ __launch_bounds__(256) void build_kernel(const unsigned int* __restrict__ binned,
                                                    const int* __restrict__ bucket_base,
                                                    int* __restrict__ csr,
                                                    int* __restrict__ offs, int N) {
  __shared__ int ncount[256], ncur[256], sscan[256];
  const int b = blockIdx.x;
  const int t = threadIdx.x;
  const int nstart = b << 8;
  const int rb = bucket_base[b], re = bucket_base[b + 1];
  ncount[t] = 0;
  __syncthreads();
  for (int idx = rb + t; idx < re; idx += 256)
    atomicAdd(&ncount[(binned[idx] >> 16) & 255], 1);
  __syncthreads();
  sscan[t] = ncount[t];
  __syncthreads();
#pragma unroll
  for (int o = 1; o < 256; o <<= 1) {
    int u = (t >= o) ? sscan[t - o] : 0;
    __syncthreads();
    sscan[t] += u;
    __syncthreads();
  }
  const int excl = sscan[t] - ncount[t];
  ncur[t] = excl;
  if (nstart + t < N) offs[nstart + t] = rb + excl;
  __syncthreads();
  for (int idx = rb + t; idx < re; idx += 256) {
    const unsigned int rec = binned[idx];
    const int p = atomicAdd(&ncur[(rec >> 16) & 255], 1);
    csr[rb + p] = (int)(rec & 0xffffu);
  }
}

// ============ prep: f32 -> bf16 convert; weight fragment packing ============
__global__ __launch_bounds__(256) void cvt_x_kernel(const float* __restrict__ X,
                                                    unsigned int* __restrict__ Xb, int n4) {
  int i = blockIdx.x * 256 + threadIdx.x;
  if (i >= n4) return;
  float4 v = ((const float4*)X)[i];
  uint2 o;
  o.x = cvt_pk_bf16(v.x, v.y);
  o.y = cvt_pk_bf16(v.z, v.w);
  ((uint2*)Xb)[i] = o;
}

// pack W [nmats][128][128] f32 -> MFMA B-fragment order bf16 (K tiles = 4)
__global__ __launch_bounds__(256) void pack_w_kernel(const float* __restrict__ W,
                                                     unsigned short* __restrict__ P,
                                                     int nmats) {
  int q = blockIdx.x * 256 + threadIdx.x;
  if (q >= nmats * 16384) return;
  int mat = q >> 14;
  int r = q & 16383;
  int e = r & 7, l = (r >> 3) & 63, ks = (r >> 9) & 3, ct = r >> 11;
  int k = ks * 32 + (l >> 4) * 8 + e;
  int n = ct * 16 + (l & 15);
  P[q] = f2bf(W[(size_t)mat * 16384 + k * DD + n]);
}

// pack out_w [384][256] f32 -> B-fragment order bf16: P[((ct*12+ks)*64+l)*8+e]
__global__ __launch_bounds__(256) void pack_wo_kernel(const float* __restrict__ W,
                                                      unsigned short* __restrict__ P) {
  int q = blockIdx.x * 256 + threadIdx.x;
  if (q >= 384 * 256) return;
  int e = q & 7, l = (q >> 3) & 63;
  int rest = q >> 9;
  int ks = rest % 12, ct = rest / 12;
  int k = ks * 32 + (l >> 4) * 8 + e;
  int n = ct * 16 + (l & 15);
  P[q] = f2bf(W[(size_t)k * 256 + n]);
}

// ============ aggregation (bf16): z[i] = h[i] + sum_{j->i} h[j] ============
__device__ __forceinline__ void bfacc8(float* a, uint4 v) {
  a[0] += __uint_as_float(v.x << 16);
  a[1] += __uint_as_float(v.x & 0xffff0000u);
  a[2] += __uint_as_float(v.y << 16);
  a[3] += __uint_as_float(v.y & 0xffff0000u);
  a[4] += __uint_as_float(v.z << 16);
  a[5] += __uint_as_float(v.z & 0xffff0000u);
  a[6] += __uint_as_float(v.w << 16);
  a[7] += __uint_as_float(v.w & 0xffff0000u);
}

__global__ __launch_bounds__(256) void agg_kernel(const uint4* __restrict__ H4,
                                                  const int* __restrict__ offs,
                                                  const int* __restrict__ csr_src,
                                                  uint4* __restrict__ Z4, int N) {
  const int node = (blockIdx.x * 256 + threadIdx.x) >> 6;
  if (node >= N) return;
  const int lane = threadIdx.x & 63;
  const int qw = lane >> 4;
  const int ql = lane & 15;

  float acc[8] = {0.f, 0.f, 0.f, 0.f, 0.f, 0.f, 0.f, 0.f};
  if (qw == 0) {
    uint4 u = H4[(size_t)node * 16 + ql];
    bfacc8(acc, u);
  }
  const int e1 = offs[node + 1];
  int e = offs[node] + qw;
  for (; e + 4 < e1; e += 8) {
    int s0 = csr_src[e];
    int s1 = csr_src[e + 4];
    uint4 a = H4[(size_t)s0 * 16 + ql];
    uint4 b = H4[(size_t)s1 * 16 + ql];
    bfacc8(acc, a);
    bfacc8(acc, b);
  }
  if (e < e1) {
    uint4 a = H4[(size_t)csr_src[e] * 16 + ql];
    bfacc8(acc, a);
  }
#pragma unroll
  for (int i = 0; i < 8; ++i) {
    acc[i] += __shfl_xor(acc[i], 16, 64);
    acc[i] += __shfl_xor(acc[i], 32, 64);
  }
  if (qw == 0) {
    uint4 o;
    o.x = cvt_pk_bf16(acc[0], acc[1]);
    o.y = cvt_pk_bf16(acc[2], acc[3]);
    o.z = cvt_pk_bf16(acc[4], acc[5]);
    o.w = cvt_pk_bf16(acc[6], acc[7]);
    Z4[(size_t)node * 16 + ql] = o;
  }
}

// ====== fused MFMA MLP: H = relu( relu(Z @ W1) @ W2 ), bf16 in/out ======
__global__ __launch_bounds__(256) void mlp_mfma_kernel(const unsigned short* Z,
                                                       const unsigned short* __restrict__ W1p,
                                                       const unsigned short* __restrict__ W2p,
                                                       unsigned short* H, int ntiles32) {
  __shared__ unsigned short zbuf[4][32 * DD];
  const int w = threadIdx.x >> 6;
  const int l = threadIdx.x & 63;
  const int tile = blockIdx.x * 4 + w;
  if (tile >= ntiles32) return;
  const size_t row0 = (size_t)tile * 32;
  unsigned short* zl = zbuf[w];

  const unsigned short* zg = Z + row0 * DD;
#pragma unroll
  for (int i = 0; i < 8; ++i) {
    const int m = i * 4 + (l >> 4);
    const int c8 = l & 15;
    short8 v = *(const short8*)(zg + m * DD + c8 * 8);
    *(short8*)&zl[m * DD + ((c8 ^ (m & 7)) << 3)] = v;
  }

  const int m_a = l & 15;
  const int g = l >> 4;

  f32x4 acc[2][8];
#pragma unroll
  for (int t2 = 0; t2 < 2; ++t2)
#pragma unroll
    for (int ct = 0; ct < 8; ++ct) acc[t2][ct] = (f32x4){0.f, 0.f, 0.f, 0.f};

#pragma unroll
  for (int ks = 0; ks < 4; ++ks) {
    const int c8 = ks * 4 + g;
    short8 a0 = *(const short8*)&zl[m_a * DD + ((c8 ^ (m_a & 7)) << 3)];
    short8 a1 = *(const short8*)&zl[(16 + m_a) * DD + ((c8 ^ (m_a & 7)) << 3)];
#pragma unroll
    for (int ct = 0; ct < 8; ++ct) {
      short8 b = *(const short8*)&W1p[(size_t)((ct * 4 + ks) * 64 + l) * 8];
      acc[0][ct] = __builtin_amdgcn_mfma_f32_16x16x32_bf16(a0, b, acc[0][ct], 0, 0, 0);
      acc[1][ct] = __builtin_amdgcn_mfma_f32_16x16x32_bf16(a1, b, acc[1][ct], 0, 0, 0);
    }
  }

#pragma unroll
  for (int t2 = 0; t2 < 2; ++t2)
#pragma unroll
    for (int ct = 0; ct < 8; ++ct) {
      const int c = ct * 16 + m_a;
#pragma unroll
      for (int r = 0; r < 4; r += 2) {
        unsigned int p = cvt_pk_bf16(fmaxf(acc[t2][ct][r], 0.f),
                                     fmaxf(acc[t2][ct][r + 1], 0.f));
        const int m0 = t2 * 16 + g * 4 + r;
        const int m1 = m0 + 1;
        zl[m0 * DD + (((c >> 3) ^ (m0 & 7)) << 3) + (c & 7)] = (unsigned short)p;
        zl[m1 * DD + (((c >> 3) ^ (m1 & 7)) << 3) + (c & 7)] = (unsigned short)(p >> 16);
      }
    }

  f32x4 acc2[2][8];
#pragma unroll
  for (int t2 = 0; t2 < 2; ++t2)
#pragma unroll
    for (int ct = 0; ct < 8; ++ct) acc2[t2][ct] = (f32x4){0.f, 0.f, 0.f, 0.f};

#pragma unroll
  for (int ks = 0; ks < 4; ++ks) {
    const int c8 = ks * 4 + g;
    short8 a0 = *(const short8*)&zl[m_a * DD + ((c8 ^ (m_a & 7)) << 3)];
    short8 a1 = *(const short8*)&zl[(16 + m_a) * DD + ((c8 ^ (m_a & 7)) << 3)];
#pragma unroll
    for (int ct = 0; ct < 8; ++ct) {
      short8 b = *(const short8*)&W2p[(size_t)((ct * 4 + ks) * 64 + l) * 8];
      acc2[0][ct] = __builtin_amdgcn_mfma_f32_16x16x32_bf16(a0, b, acc2[0][ct], 0, 0, 0);
      acc2[1][ct] = __builtin_amdgcn_mfma_f32_16x16x32_bf16(a1, b, acc2[1][ct], 0, 0, 0);
    }
  }

#pragma unroll
  for (int t2 = 0; t2 < 2; ++t2)
#pragma unroll
    for (int ct = 0; ct < 8; ++ct) {
      const int c = ct * 16 + m_a;
#pragma unroll
      for (int r = 0; r < 4; r += 2) {
        unsigned int p = cvt_pk_bf16(fmaxf(acc2[t2][ct][r], 0.f),
                                     fmaxf(acc2[t2][ct][r + 1], 0.f));
        const int m0 = t2 * 16 + g * 4 + r;
        const int m1 = m0 + 1;
        zl[m0 * DD + (((c >> 3) ^ (m0 & 7)) << 3) + (c & 7)] = (unsigned short)p;
        zl[m1 * DD + (((c >> 3) ^ (m1 & 7)) << 3) + (c & 7)] = (unsigned short)(p >> 16);
      }
    }
  unsigned short* hg = H + row0 * DD;
#pragma unroll
  for (int i = 0; i < 8; ++i) {
    const int m = i * 4 + (l >> 4);
    const int c8 = l & 15;
    short8 v = *(const short8*)&zl[m * DD + ((c8 ^ (m & 7)) << 3)];
    *(short8*)(hg + m * DD + c8 * 8) = v;
  }
}

// ============ pooled readout -> bf16 [G][384] rows: [gmax|gmean|gsum] ============
__device__ __forceinline__ int lower_bound_dev(const int* a, int n, int v) {
  int lo = 0, hi = n;
  while (lo < hi) {
    int mid = (lo + hi) >> 1;
    if (a[mid] < v) lo = mid + 1; else hi = mid;
  }
  return lo;
}

__global__ __launch_bounds__(256) void pool_kernel(const unsigned int* __restrict__ H2,
                                                   const int* __restrict__ batch,
                                                   unsigned int* __restrict__ pooled_bf,
                                                   int N) {
  const int g = blockIdx.x;
  __shared__ int sRange[2];
  if (threadIdx.x < 2) sRange[threadIdx.x] = lower_bound_dev(batch, N, g + threadIdx.x);
  __syncthreads();
  const int lo = sRange[0], hi = sRange[1];
  const int cp = threadIdx.x & 63;
  const int sl = threadIdx.x >> 6;
  float sx = 0.f, sy = 0.f, mx = 0.f, my = 0.f;
  for (int r = lo + sl; r < hi; r += 4) {
    unsigned int u = H2[(size_t)r * 64 + cp];
    float a = __uint_as_float(u << 16);
    float b = __uint_as_float(u & 0xffff0000u);
    sx += a; sy += b;
    mx = fmaxf(mx, a); my = fmaxf(my, b);
  }
  __shared__ float sS[3][DD], sM[3][DD];
  if (sl > 0) {
    sS[sl - 1][cp * 2] = sx; sS[sl - 1][cp * 2 + 1] = sy;
    sM[sl - 1][cp * 2] = mx; sM[sl - 1][cp * 2 + 1] = my;
  }
  __syncthreads();
  if (sl == 0) {
#pragma unroll
    for (int j = 0; j < 3; ++j) {
      sx += sS[j][cp * 2]; sy += sS[j][cp * 2 + 1];
      mx = fmaxf(mx, sM[j][cp * 2]); my = fmaxf(my, sM[j][cp * 2 + 1]);
    }
    const float cnt = fmaxf((float)(hi - lo), 1.f);
    const size_t pb = (size_t)g * 192;  // 384 bf16 = 192 uints
    pooled_bf[pb + cp] = cvt_pk_bf16(mx, my);
    pooled_bf[pb + 64 + cp] = cvt_pk_bf16(sx / cnt, sy / cnt);
    pooled_bf[pb + 128 + cp] = cvt_pk_bf16(sx, sy);
  }
}

// ============ final MFMA GEMM: out[G,256] = pooled[G,384] @ out_w + bo ============
// 4 blocks x 4 waves; wave owns one 16-row tile x all 16 col-tiles, K=384.
__global__ __launch_bounds__(256) void final_mfma_kernel(const unsigned short* __restrict__ Pb,
                                                         const unsigned short* __restrict__ Wop,
                                                         const float* __restrict__ bo,
                                                         float* __restrict__ out, int ntile) {
  const int w = threadIdx.x >> 6;
  const int l = threadIdx.x & 63;
  const int tile = blockIdx.x * 4 + w;
  if (tile >= ntile) return;
  const int row0 = tile * 16;
  const int m_a = l & 15;
  const int g = l >> 4;

  f32x4 acc[16];
#pragma unroll
  for (int ct = 0; ct < 16; ++ct) acc[ct] = (f32x4){0.f, 0.f, 0.f, 0.f};

#pragma unroll
  for (int ks = 0; ks < 12; ++ks) {
    short8 a = *(const short8*)&Pb[((size_t)(row0 + m_a) * 384) + ks * 32 + g * 8];
#pragma unroll
    for (int ct = 0; ct < 16; ++ct) {
      short8 b = *(const short8*)&Wop[(size_t)((ct * 12 + ks) * 64 + l) * 8];
      acc[ct] = __builtin_amdgcn_mfma_f32_16x16x32_bf16(a, b, acc[ct], 0, 0, 0);
    }
  }

#pragma unroll
  for (int ct = 0; ct < 16; ++ct) {
    const int n = ct * 16 + m_a;
    const float bias = bo[n];
#pragma unroll
    for (int r = 0; r < 4; ++r) {
      const int row = row0 + g * 4 + r;
      out[(size_t)row * 256 + n] = acc[ct][r] + bias;
    }
  }
}

// ======================= launch =======================
extern "C" void kernel_launch(void* const* d_in, const int* in_sizes, int n_in,
                              void* d_out, int out_size, void* d_ws, size_t ws_size,
                              hipStream_t stream) {
  const float* x     = (const float*)d_in[0];
  const int*   ei    = (const int*)d_in[1];
  const int*   batch = (const int*)d_in[2];
  const float* w1_0  = (const float*)d_in[3];
  const float* w2_0  = (const float*)d_in[4];
  const float* gw1   = (const float*)d_in[5];
  const float* gw2   = (const float*)d_in[6];
  const float* out_w = (const float*)d_in[7];
  const float* out_b = (const float*)d_in[8];

  const int N   = in_sizes[0] / DD;        // 50000 (fits 16-bit src pack)
  const int E   = in_sizes[1] / 2;
  const int Lm1 = in_sizes[5] / (DD * DD);
  const int OUT = in_sizes[7] / (3 * DD);  // 256
  const int G   = out_size / OUT;          // 256

  const int* src = ei;
  const int* dst = ei + E;
  const int NB = (N + 255) >> 8;
  const int nmats = 2 + 2 * Lm1;
  const int Npad = (N + 31) & ~31;

  char* p = (char*)d_ws;
  auto take = [&](size_t bytes) -> char* {
    char* r = p;
    p += (bytes + 511) & ~(size_t)511;
    return r;
  };
  int* cnt         = (int*)take((size_t)NB * 4);
  int* bucket_base = (int*)take((size_t)(NB + 1) * 4);
  int* cursor      = (int*)take((size_t)NB * 4);
  unsigned int* binned = (unsigned int*)take((size_t)E * 4);
  int* csr         = (int*)take((size_t)E * 4);
  int* offs        = (int*)take((size_t)(N + 1) * 4);
  unsigned short* packW = (unsigned short*)take((size_t)nmats * 16384 * 2);
  unsigned short* packWo = (unsigned short*)take((size_t)384 * 256 * 2);
  unsigned short* xb    = (unsigned short*)take((size_t)Npad * DD * 2);
  unsigned short* bufA  = (unsigned short*)take((size_t)Npad * DD * 2);
  unsigned short* bufB  = (unsigned short*)take((size_t)Npad * DD * 2);
  unsigned int* pooled_bf = (unsigned int*)take((size_t)G * 192 * 4);

  // ---- prep: weight packing + x conversion ----
  pack_w_kernel<<<(1 * 16384 + 255) / 256, 256, 0, stream>>>(w1_0, packW, 1);
  pack_w_kernel<<<(1 * 16384 + 255) / 256, 256, 0, stream>>>(w2_0, packW + 16384, 1);
  pack_w_kernel<<<(Lm1 * 16384 + 255) / 256, 256, 0, stream>>>(gw1, packW + 2 * 16384, Lm1);
  pack_w_kernel<<<(Lm1 * 16384 + 255) / 256, 256, 0, stream>>>(gw2, packW + (size_t)(2 + Lm1) * 16384, Lm1);
  pack_wo_kernel<<<(384 * 256 + 255) / 256, 256, 0, stream>>>(out_w, packWo);
  cvt_x_kernel<<<(N * DD / 4 + 255) / 256, 256, 0, stream>>>(x, (unsigned int*)xb, N * DD / 4);

  // ---- CSR build (bucketed) ----
  hipMemsetAsync(cnt, 0, (size_t)NB * 4, stream);
  bhist_kernel<<<196, 256, 0, stream>>>(dst, cnt, E, NB);
  bscan_kernel<<<1, 256, 0, stream>>>(cnt, bucket_base, cursor, offs, NB, N);
  bin_kernel<<<(E + BIN_CH - 1) / BIN_CH, 256, 0, stream>>>(src, dst, cursor, binned, E, NB);
  build_kernel<<<NB, 256, 0, stream>>>(binned, bucket_base, csr, offs, N);

  // ---- 3 GIN layers (agg -> fused MFMA MLP, in-place) ----
  const int ntiles32 = Npad / 32;
  const int mlp_blocks = (ntiles32 + 3) / 4;
  const unsigned short* hcur = xb;
  unsigned short* bufs[2] = {bufA, bufB};
  for (int l = 0; l <= Lm1; ++l) {
    unsigned short* zb = bufs[l & 1];
    agg_kernel<<<(N + 3) / 4, 256, 0, stream>>>((const uint4*)hcur, offs, csr,
                                                (uint4*)zb, N);
    const unsigned short* W1p = packW + (size_t)((l == 0) ? 0 : (2 + (l - 1))) * 16384;
    const unsigned short* W2p = packW + (size_t)((l == 0) ? 1 : (2 + Lm1 + (l - 1))) * 16384;
    mlp_mfma_kernel<<<mlp_blocks, 256, 0, stream>>>(zb, W1p, W2p, zb, ntiles32);
    hcur = zb;
  }

  // ---- readout ----
  pool_kernel<<<G, 256, 0, stream>>>((const unsigned int*)hcur, batch, pooled_bf, N);
  const int ntile_f = (G + 15) / 16;
  final_mfma_kernel<<<(ntile_f + 3) / 4, 256, 0, stream>>>(
      (const unsigned short*)pooled_bf, packWo, out_b, (float*)d_out, ntile_f);
}

// Round 7
// 230.988 us; speedup vs baseline: 1.1986x; 1.1986x over previous
//
#include <hip/hip_runtime.h>

#define DD 128
#define BIN_CH 2048  // edges staged per bin block

typedef __attribute__((ext_vector_type(8))) short short8;
typedef __attribute__((ext_vector_type(4))) float f32x4;

__device__ __forceinline__ unsigned short f2bf(float x) {
  unsigned int b = __float_as_uint(x);
  b += 0x7fffu + ((b >> 16) & 1u);
  return (unsigned short)(b >> 16);
}

__device__ __forceinline__ unsigned int cvt_pk_bf16(float lo, float hi) {
  unsigned int d;
  asm("v_cvt_pk_bf16_f32 %0, %1, %2" : "=v"(d) : "v"(lo), "v"(hi));
  return d;
}

// ============== CSR build, bucketed (bucket = dst >> 8, <=256 buckets) ==============
__global__ __launch_bounds__(256) void bhist_kernel(const int* __restrict__ dst,
                                                    int* __restrict__ cnt, int E, int NB) {
  __shared__ int lh[256];
  const int t = threadIdx.x;
  lh[t] = 0;
  __syncthreads();
  const int e4 = E >> 2;
  const int4* d4 = (const int4*)dst;
  for (int i = blockIdx.x * 256 + t; i < e4; i += gridDim.x * 256) {
    int4 v = d4[i];
    atomicAdd(&lh[v.x >> 8], 1);
    atomicAdd(&lh[v.y >> 8], 1);
    atomicAdd(&lh[v.z >> 8], 1);
    atomicAdd(&lh[v.w >> 8], 1);
  }
  if (blockIdx.x == 0) {
    for (int i = (e4 << 2) + t; i < E; i += 256) atomicAdd(&lh[dst[i] >> 8], 1);
  }
  __syncthreads();
  if (t < NB && lh[t]) atomicAdd(&cnt[t], lh[t]);
}

__global__ __launch_bounds__(256) void bscan_kernel(const int* __restrict__ cnt,
                                                    int* __restrict__ bucket_base,
                                                    int* __restrict__ cursor,
                                                    int* __restrict__ offs, int NB, int N) {
  __shared__ int s[256];
  const int t = threadIdx.x;
  int v = (t < NB) ? cnt[t] : 0;
  s[t] = v;
  __syncthreads();
#pragma unroll
  for (int o = 1; o < 256; o <<= 1) {
    int u = (t >= o) ? s[t - o] : 0;
    __syncthreads();
    s[t] += u;
    __syncthreads();
  }
  if (t < NB) {
    bucket_base[t] = s[t] - v;
    cursor[t] = s[t] - v;
  }
  if (t == 255) {
    bucket_base[NB] = s[255];
    offs[N] = s[255];
  }
}

__global__ __launch_bounds__(256) void bin_kernel(const int* __restrict__ src,
                                                  const int* __restrict__ dst,
                                                  int* __restrict__ cursor,
                                                  unsigned int* __restrict__ binned,
                                                  int E, int NB) {
  __shared__ int lcount[256], lbase[256], lcur[256], lgbase[256], sscan[256];
  __shared__ unsigned int stage[BIN_CH];
  const int t = threadIdx.x;
  const int cb = blockIdx.x * BIN_CH;
  lcount[t] = 0;
  __syncthreads();

  int sv[BIN_CH / 256], dv[BIN_CH / 256];
#pragma unroll
  for (int i = 0; i < BIN_CH / 256; ++i) {
    const int idx = cb + i * 256 + t;
    if (idx < E) {
      sv[i] = src[idx];
      dv[i] = dst[idx];
      atomicAdd(&lcount[dv[i] >> 8], 1);
    } else {
      sv[i] = -1;
    }
  }
  __syncthreads();
  sscan[t] = lcount[t];
  __syncthreads();
#pragma unroll
  for (int o = 1; o < 256; o <<= 1) {
    int u = (t >= o) ? sscan[t - o] : 0;
    __syncthreads();
    sscan[t] += u;
    __syncthreads();
  }
  lbase[t] = sscan[t] - lcount[t];
  lcur[t] = lbase[t];
  __syncthreads();
#pragma unroll
  for (int i = 0; i < BIN_CH / 256; ++i) {
    if (sv[i] >= 0) {
      const int b = dv[i] >> 8;
      const int pos = atomicAdd(&lcur[b], 1);
      stage[pos] = (unsigned)sv[i] | ((unsigned)(dv[i] & 255) << 16) | ((unsigned)b << 24);
    }
  }
  __syncthreads();
  if (t < NB && lcount[t]) lgbase[t] = atomicAdd(&cursor[t], lcount[t]);
  __syncthreads();
  const int total = (cb + BIN_CH <= E) ? BIN_CH : (E - cb);
  for (int idx = t; idx < total; idx += 256) {
    const unsigned int rec = stage[idx];
    const int b = rec >> 24;
    binned[lgbase[b] + (idx - lbase[b])] = rec;
  }
}

__global__ __launch_bounds__(256) void build_kernel(const unsigned int* __restrict__ binned,
                                                    const int* __restrict__ bucket_base,
                                                    int* __restrict__ csr,
                                                    int* __restrict__ offs, int N) {
  __shared__ int ncount[256], ncur[256], sscan[256];
  const int b = blockIdx.x;
  const int t = threadIdx.x;
  const int nstart = b << 8;
  const int rb = bucket_base[b], re = bucket_base[b + 1];
  ncount[t] = 0;
  __syncthreads();
  for (int idx = rb + t; idx < re; idx += 256)
    atomicAdd(&ncount[(binned[idx] >> 16) & 255], 1);
  __syncthreads();
  sscan[t] = ncount[t];
  __syncthreads();
#pragma unroll
  for (int o = 1; o < 256; o <<= 1) {
    int u = (t >= o) ? sscan[t - o] : 0;
    __syncthreads();
    sscan[t] += u;
    __syncthreads();
  }
  const int excl = sscan[t] - ncount[t];
  ncur[t] = excl;
  if (nstart + t < N) offs[nstart + t] = rb + excl;
  __syncthreads();
  for (int idx = rb + t; idx < re; idx += 256) {
    const unsigned int rec = binned[idx];
    const int p = atomicAdd(&ncur[(rec >> 16) & 255], 1);
    csr[rb + p] = (int)(rec & 0xffffu);
  }
}

// ============ prep: f32 -> bf16 convert; weight fragment packing ============
__global__ __launch_bounds__(256) void cvt_x_kernel(const float* __restrict__ X,
                                                    unsigned int* __restrict__ Xb, int n4) {
  int i = blockIdx.x * 256 + threadIdx.x;
  if (i >= n4) return;
  float4 v = ((const float4*)X)[i];
  uint2 o;
  o.x = cvt_pk_bf16(v.x, v.y);
  o.y = cvt_pk_bf16(v.z, v.w);
  ((uint2*)Xb)[i] = o;
}

// pack W [nmats][128][128] f32 -> MFMA B-fragment order bf16 (K tiles = 4)
__global__ __launch_bounds__(256) void pack_w_kernel(const float* __restrict__ W,
                                                     unsigned short* __restrict__ P,
                                                     int nmats) {
  int q = blockIdx.x * 256 + threadIdx.x;
  if (q >= nmats * 16384) return;
  int mat = q >> 14;
  int r = q & 16383;
  int e = r & 7, l = (r >> 3) & 63, ks = (r >> 9) & 3, ct = r >> 11;
  int k = ks * 32 + (l >> 4) * 8 + e;
  int n = ct * 16 + (l & 15);
  P[q] = f2bf(W[(size_t)mat * 16384 + k * DD + n]);
}

// pack out_w [384][256] f32 -> B-fragment order bf16: P[((ct*12+ks)*64+l)*8+e]
__global__ __launch_bounds__(256) void pack_wo_kernel(const float* __restrict__ W,
                                                      unsigned short* __restrict__ P) {
  int q = blockIdx.x * 256 + threadIdx.x;
  if (q >= 384 * 256) return;
  int e = q & 7, l = (q >> 3) & 63;
  int rest = q >> 9;
  int ks = rest % 12, ct = rest / 12;
  int k = ks * 32 + (l >> 4) * 8 + e;
  int n = ct * 16 + (l & 15);
  P[q] = f2bf(W[(size_t)k * 256 + n]);
}

// ============ aggregation (bf16): z[i] = h[i] + sum_{j->i} h[j] ============
__device__ __forceinline__ void bfacc8(float* a, uint4 v) {
  a[0] += __uint_as_float(v.x << 16);
  a[1] += __uint_as_float(v.x & 0xffff0000u);
  a[2] += __uint_as_float(v.y << 16);
  a[3] += __uint_as_float(v.y & 0xffff0000u);
  a[4] += __uint_as_float(v.z << 16);
  a[5] += __uint_as_float(v.z & 0xffff0000u);
  a[6] += __uint_as_float(v.w << 16);
  a[7] += __uint_as_float(v.w & 0xffff0000u);
}

__global__ __launch_bounds__(256) void agg_kernel(const uint4* __restrict__ H4,
                                                  const int* __restrict__ offs,
                                                  const int* __restrict__ csr_src,
                                                  uint4* __restrict__ Z4, int N) {
  const int node = (blockIdx.x * 256 + threadIdx.x) >> 6;
  if (node >= N) return;
  const int lane = threadIdx.x & 63;
  const int qw = lane >> 4;
  const int ql = lane & 15;

  float acc[8] = {0.f, 0.f, 0.f, 0.f, 0.f, 0.f, 0.f, 0.f};
  if (qw == 0) {
    uint4 u = H4[(size_t)node * 16 + ql];
    bfacc8(acc, u);
  }
  const int e1 = offs[node + 1];
  int e = offs[node] + qw;
  for (; e + 4 < e1; e += 8) {
    int s0 = csr_src[e];
    int s1 = csr_src[e + 4];
    uint4 a = H4[(size_t)s0 * 16 + ql];
    uint4 b = H4[(size_t)s1 * 16 + ql];
    bfacc8(acc, a);
    bfacc8(acc, b);
  }
  if (e < e1) {
    uint4 a = H4[(size_t)csr_src[e] * 16 + ql];
    bfacc8(acc, a);
  }
#pragma unroll
  for (int i = 0; i < 8; ++i) {
    acc[i] += __shfl_xor(acc[i], 16, 64);
    acc[i] += __shfl_xor(acc[i], 32, 64);
  }
  if (qw == 0) {
    uint4 o;
    o.x = cvt_pk_bf16(acc[0], acc[1]);
    o.y = cvt_pk_bf16(acc[2], acc[3]);
    o.z = cvt_pk_bf16(acc[4], acc[5]);
    o.w = cvt_pk_bf16(acc[6], acc[7]);
    Z4[(size_t)node * 16 + ql] = o;
  }
}

// ====== fused MFMA MLP: H = relu( relu(Z @ W1) @ W2 ), bf16 in/out ======
__global__ __launch_bounds__(256) void mlp_mfma_kernel(const unsigned short* Z,
                                                       const unsigned short* __restrict__ W1p,
                                                       const unsigned short* __restrict__ W2p,
                                                       unsigned short* H, int ntiles32) {
  __shared__ unsigned short zbuf[4][32 * DD];
  const int w = threadIdx.x >> 6;
  const int l = threadIdx.x & 63;
  const int tile = blockIdx.x * 4 + w;
  if (tile >= ntiles32) return;
  const size_t row0 = (size_t)tile * 32;
  unsigned short* zl = zbuf[w];

  const unsigned short* zg = Z + row0 * DD;
#pragma unroll
  for (int i = 0; i < 8; ++i) {
    const int m = i * 4 + (l >> 4);
    const int c8 = l & 15;
    short8 v = *(const short8*)(zg + m * DD + c8 * 8);
    *(short8*)&zl[m * DD + ((c8 ^ (m & 7)) << 3)] = v;
  }

  const int m_a = l & 15;
  const int g = l >> 4;

  f32x4 acc[2][8];
#pragma unroll
  for (int t2 = 0; t2 < 2; ++t2)
#pragma unroll
    for (int ct = 0; ct < 8; ++ct) acc[t2][ct] = (f32x4){0.f, 0.f, 0.f, 0.f};

#pragma unroll
  for (int ks = 0; ks < 4; ++ks) {
    const int c8 = ks * 4 + g;
    short8 a0 = *(const short8*)&zl[m_a * DD + ((c8 ^ (m_a & 7)) << 3)];
    short8 a1 = *(const short8*)&zl[(16 + m_a) * DD + ((c8 ^ (m_a & 7)) << 3)];
#pragma unroll
    for (int ct = 0; ct < 8; ++ct) {
      short8 b = *(const short8*)&W1p[(size_t)((ct * 4 + ks) * 64 + l) * 8];
      acc[0][ct] = __builtin_amdgcn_mfma_f32_16x16x32_bf16(a0, b, acc[0][ct], 0, 0, 0);
      acc[1][ct] = __builtin_amdgcn_mfma_f32_16x16x32_bf16(a1, b, acc[1][ct], 0, 0, 0);
    }
  }

#pragma unroll
  for (int t2 = 0; t2 < 2; ++t2)
#pragma unroll
    for (int ct = 0; ct < 8; ++ct) {
      const int c = ct * 16 + m_a;
#pragma unroll
      for (int r = 0; r < 4; r += 2) {
        unsigned int p = cvt_pk_bf16(fmaxf(acc[t2][ct][r], 0.f),
                                     fmaxf(acc[t2][ct][r + 1], 0.f));
        const int m0 = t2 * 16 + g * 4 + r;
        const int m1 = m0 + 1;
        zl[m0 * DD + (((c >> 3) ^ (m0 & 7)) << 3) + (c & 7)] = (unsigned short)p;
        zl[m1 * DD + (((c >> 3) ^ (m1 & 7)) << 3) + (c & 7)] = (unsigned short)(p >> 16);
      }
    }

  f32x4 acc2[2][8];
#pragma unroll
  for (int t2 = 0; t2 < 2; ++t2)
#pragma unroll
    for (int ct = 0; ct < 8; ++ct) acc2[t2][ct] = (f32x4){0.f, 0.f, 0.f, 0.f};

#pragma unroll
  for (int ks = 0; ks < 4; ++ks) {
    const int c8 = ks * 4 + g;
    short8 a0 = *(const short8*)&zl[m_a * DD + ((c8 ^ (m_a & 7)) << 3)];
    short8 a1 = *(const short8*)&zl[(16 + m_a) * DD + ((c8 ^ (m_a & 7)) << 3)];
#pragma unroll
    for (int ct = 0; ct < 8; ++ct) {
      short8 b = *(const short8*)&W2p[(size_t)((ct * 4 + ks) * 64 + l) * 8];
      acc2[0][ct] = __builtin_amdgcn_mfma_f32_16x16x32_bf16(a0, b, acc2[0][ct], 0, 0, 0);
      acc2[1][ct] = __builtin_amdgcn_mfma_f32_16x16x32_bf16(a1, b, acc2[1][ct], 0, 0, 0);
    }
  }

#pragma unroll
  for (int t2 = 0; t2 < 2; ++t2)
#pragma unroll
    for (int ct = 0; ct < 8; ++ct) {
      const int c = ct * 16 + m_a;
#pragma unroll
      for (int r = 0; r < 4; r += 2) {
        unsigned int p = cvt_pk_bf16(fmaxf(acc2[t2][ct][r], 0.f),
                                     fmaxf(acc2[t2][ct][r + 1], 0.f));
        const int m0 = t2 * 16 + g * 4 + r;
        const int m1 = m0 + 1;
        zl[m0 * DD + (((c >> 3) ^ (m0 & 7)) << 3) + (c & 7)] = (unsigned short)p;
        zl[m1 * DD + (((c >> 3) ^ (m1 & 7)) << 3) + (c & 7)] = (unsigned short)(p >> 16);
      }
    }
  unsigned short* hg = H + row0 * DD;
#pragma unroll
  for (int i = 0; i < 8; ++i) {
    const int m = i * 4 + (l >> 4);
    const int c8 = l & 15;
    short8 v = *(const short8*)&zl[m * DD + ((c8 ^ (m & 7)) << 3)];
    *(short8*)(hg + m * DD + c8 * 8) = v;
  }
}

// ============ pooled readout -> bf16 [G][384] rows: [gmax|gmean|gsum] ============
__device__ __forceinline__ int lower_bound_dev(const int* a, int n, int v) {
  int lo = 0, hi = n;
  while (lo < hi) {
    int mid = (lo + hi) >> 1;
    if (a[mid] < v) lo = mid + 1; else hi = mid;
  }
  return lo;
}

__global__ __launch_bounds__(256) void pool_kernel(const unsigned int* __restrict__ H2,
                                                   const int* __restrict__ batch,
                                                   unsigned int* __restrict__ pooled_bf,
                                                   int N) {
  const int g = blockIdx.x;
  __shared__ int sRange[2];
  if (threadIdx.x < 2) sRange[threadIdx.x] = lower_bound_dev(batch, N, g + threadIdx.x);
  __syncthreads();
  const int lo = sRange[0], hi = sRange[1];
  const int cp = threadIdx.x & 63;
  const int sl = threadIdx.x >> 6;
  float sx = 0.f, sy = 0.f, mx = 0.f, my = 0.f;
  for (int r = lo + sl; r < hi; r += 4) {
    unsigned int u = H2[(size_t)r * 64 + cp];
    float a = __uint_as_float(u << 16);
    float b = __uint_as_float(u & 0xffff0000u);
    sx += a; sy += b;
    mx = fmaxf(mx, a); my = fmaxf(my, b);
  }
  __shared__ float sS[3][DD], sM[3][DD];
  if (sl > 0) {
    sS[sl - 1][cp * 2] = sx; sS[sl - 1][cp * 2 + 1] = sy;
    sM[sl - 1][cp * 2] = mx; sM[sl - 1][cp * 2 + 1] = my;
  }
  __syncthreads();
  if (sl == 0) {
#pragma unroll
    for (int j = 0; j < 3; ++j) {
      sx += sS[j][cp * 2]; sy += sS[j][cp * 2 + 1];
      mx = fmaxf(mx, sM[j][cp * 2]); my = fmaxf(my, sM[j][cp * 2 + 1]);
    }
    const float cnt = fmaxf((float)(hi - lo), 1.f);
    const size_t pb = (size_t)g * 192;  // 384 bf16 = 192 uints
    pooled_bf[pb + cp] = cvt_pk_bf16(mx, my);
    pooled_bf[pb + 64 + cp] = cvt_pk_bf16(sx / cnt, sy / cnt);
    pooled_bf[pb + 128 + cp] = cvt_pk_bf16(sx, sy);
  }
}

// ============ final MFMA GEMM: out[G,256] = pooled[G,384] @ out_w + bo ============
// grid = (G/16 row-tiles) x 4 col-groups; 4 waves/block; each wave owns one
// 16x16 output tile (K=384 -> 12 MFMA, 24 independent 16B loads).
__global__ __launch_bounds__(256) void final_mfma_kernel(const unsigned short* __restrict__ Pb,
                                                         const unsigned short* __restrict__ Wop,
                                                         const float* __restrict__ bo,
                                                         float* __restrict__ out, int G) {
  const int w = threadIdx.x >> 6;
  const int l = threadIdx.x & 63;
  const int rt = blockIdx.x >> 2;       // row tile
  const int cg = blockIdx.x & 3;        // col group
  const int ct = cg * 4 + w;            // col tile 0..15
  const int row0 = rt * 16;
  const int m_a = l & 15;
  const int g = l >> 4;

  f32x4 acc = (f32x4){0.f, 0.f, 0.f, 0.f};
#pragma unroll
  for (int ks = 0; ks < 12; ++ks) {
    short8 a = *(const short8*)&Pb[((size_t)(row0 + m_a) * 384) + ks * 32 + g * 8];
    short8 b = *(const short8*)&Wop[(size_t)((ct * 12 + ks) * 64 + l) * 8];
    acc = __builtin_amdgcn_mfma_f32_16x16x32_bf16(a, b, acc, 0, 0, 0);
  }

  const int n = ct * 16 + m_a;
  const float bias = bo[n];
#pragma unroll
  for (int r = 0; r < 4; ++r) {
    const int row = row0 + g * 4 + r;
    if (row < G) out[(size_t)row * 256 + n] = acc[r] + bias;
  }
}

// ======================= launch =======================
extern "C" void kernel_launch(void* const* d_in, const int* in_sizes, int n_in,
                              void* d_out, int out_size, void* d_ws, size_t ws_size,
                              hipStream_t stream) {
  const float* x     = (const float*)d_in[0];
  const int*   ei    = (const int*)d_in[1];
  const int*   batch = (const int*)d_in[2];
  const float* w1_0  = (const float*)d_in[3];
  const float* w2_0  = (const float*)d_in[4];
  const float* gw1   = (const float*)d_in[5];
  const float* gw2   = (const float*)d_in[6];
  const float* out_w = (const float*)d_in[7];
  const float* out_b = (const float*)d_in[8];

  const int N   = in_sizes[0] / DD;        // 50000 (fits 16-bit src pack)
  const int E   = in_sizes[1] / 2;
  const int Lm1 = in_sizes[5] / (DD * DD);
  const int OUT = in_sizes[7] / (3 * DD);  // 256
  const int G   = out_size / OUT;          // 256

  const int* src = ei;
  const int* dst = ei + E;
  const int NB = (N + 255) >> 8;
  const int nmats = 2 + 2 * Lm1;
  const int Npad = (N + 31) & ~31;
  const int Gpad = (G + 15) & ~15;

  char* p = (char*)d_ws;
  auto take = [&](size_t bytes) -> char* {
    char* r = p;
    p += (bytes + 511) & ~(size_t)511;
    return r;
  };
  int* cnt         = (int*)take((size_t)NB * 4);
  int* bucket_base = (int*)take((size_t)(NB + 1) * 4);
  int* cursor      = (int*)take((size_t)NB * 4);
  unsigned int* binned = (unsigned int*)take((size_t)E * 4);
  int* csr         = (int*)take((size_t)E * 4);
  int* offs        = (int*)take((size_t)(N + 1) * 4);
  unsigned short* packW = (unsigned short*)take((size_t)nmats * 16384 * 2);
  unsigned short* packWo = (unsigned short*)take((size_t)384 * 256 * 2);
  unsigned short* xb    = (unsigned short*)take((size_t)Npad * DD * 2);
  unsigned short* bufA  = (unsigned short*)take((size_t)Npad * DD * 2);
  unsigned short* bufB  = (unsigned short*)take((size_t)Npad * DD * 2);
  unsigned int* pooled_bf = (unsigned int*)take((size_t)Gpad * 192 * 4);

  // ---- prep: weight packing + x conversion ----
  pack_w_kernel<<<(1 * 16384 + 255) / 256, 256, 0, stream>>>(w1_0, packW, 1);
  pack_w_kernel<<<(1 * 16384 + 255) / 256, 256, 0, stream>>>(w2_0, packW + 16384, 1);
  pack_w_kernel<<<(Lm1 * 16384 + 255) / 256, 256, 0, stream>>>(gw1, packW + 2 * 16384, Lm1);
  pack_w_kernel<<<(Lm1 * 16384 + 255) / 256, 256, 0, stream>>>(gw2, packW + (size_t)(2 + Lm1) * 16384, Lm1);
  pack_wo_kernel<<<(384 * 256 + 255) / 256, 256, 0, stream>>>(out_w, packWo);
  cvt_x_kernel<<<(N * DD / 4 + 255) / 256, 256, 0, stream>>>(x, (unsigned int*)xb, N * DD / 4);

  // ---- CSR build (bucketed) ----
  hipMemsetAsync(cnt, 0, (size_t)NB * 4, stream);
  bhist_kernel<<<196, 256, 0, stream>>>(dst, cnt, E, NB);
  bscan_kernel<<<1, 256, 0, stream>>>(cnt, bucket_base, cursor, offs, NB, N);
  bin_kernel<<<(E + BIN_CH - 1) / BIN_CH, 256, 0, stream>>>(src, dst, cursor, binned, E, NB);
  build_kernel<<<NB, 256, 0, stream>>>(binned, bucket_base, csr, offs, N);

  // ---- 3 GIN layers (agg -> fused MFMA MLP, in-place) ----
  const int ntiles32 = Npad / 32;
  const int mlp_blocks = (ntiles32 + 3) / 4;
  const unsigned short* hcur = xb;
  unsigned short* bufs[2] = {bufA, bufB};
  for (int l = 0; l <= Lm1; ++l) {
    unsigned short* zb = bufs[l & 1];
    agg_kernel<<<(N + 3) / 4, 256, 0, stream>>>((const uint4*)hcur, offs, csr,
                                                (uint4*)zb, N);
    const unsigned short* W1p = packW + (size_t)((l == 0) ? 0 : (2 + (l - 1))) * 16384;
    const unsigned short* W2p = packW + (size_t)((l == 0) ? 1 : (2 + Lm1 + (l - 1))) * 16384;
    mlp_mfma_kernel<<<mlp_blocks, 256, 0, stream>>>(zb, W1p, W2p, zb, ntiles32);
    hcur = zb;
  }

  // ---- readout ----
  pool_kernel<<<G, 256, 0, stream>>>((const unsigned int*)hcur, batch, pooled_bf, N);
  final_mfma_kernel<<<(Gpad / 16) * 4, 256, 0, stream>>>(
      (const unsigned short*)pooled_bf, packWo, out_b, (float*)d_out, G);
}

// Round 8
// 190.998 us; speedup vs baseline: 1.4495x; 1.2094x over previous
//
#include <hip/hip_runtime.h>

#define DD 128
#define BIN_CH 2048  // edges staged per bin block

typedef __attribute__((ext_vector_type(8))) short short8;
typedef __attribute__((ext_vector_type(4))) float f32x4;

__device__ __forceinline__ unsigned short f2bf(float x) {
  unsigned int b = __float_as_uint(x);
  b += 0x7fffu + ((b >> 16) & 1u);
  return (unsigned short)(b >> 16);
}

__device__ __forceinline__ unsigned int cvt_pk_bf16(float lo, float hi) {
  unsigned int d;
  asm("v_cvt_pk_bf16_f32 %0, %1, %2" : "=v"(d) : "v"(lo), "v"(hi));
  return d;
}

// ============== CSR build, bucketed (bucket = dst >> 8, <=256 buckets) ==============
__global__ __launch_bounds__(256) void bhist_kernel(const int* __restrict__ dst,
                                                    int* __restrict__ cnt, int E, int NB) {
  __shared__ int lh[256];
  const int t = threadIdx.x;
  lh[t] = 0;
  __syncthreads();
  const int e4 = E >> 2;
  const int4* d4 = (const int4*)dst;
  for (int i = blockIdx.x * 256 + t; i < e4; i += gridDim.x * 256) {
    int4 v = d4[i];
    atomicAdd(&lh[v.x >> 8], 1);
    atomicAdd(&lh[v.y >> 8], 1);
    atomicAdd(&lh[v.z >> 8], 1);
    atomicAdd(&lh[v.w >> 8], 1);
  }
  if (blockIdx.x == 0) {
    for (int i = (e4 << 2) + t; i < E; i += 256) atomicAdd(&lh[dst[i] >> 8], 1);
  }
  __syncthreads();
  if (t < NB && lh[t]) atomicAdd(&cnt[t], lh[t]);
}

__global__ __launch_bounds__(256) void bscan_kernel(const int* __restrict__ cnt,
                                                    int* __restrict__ bucket_base,
                                                    int* __restrict__ cursor,
                                                    int* __restrict__ offs, int NB, int N) {
  __shared__ int s[256];
  const int t = threadIdx.x;
  int v = (t < NB) ? cnt[t] : 0;
  s[t] = v;
  __syncthreads();
#pragma unroll
  for (int o = 1; o < 256; o <<= 1) {
    int u = (t >= o) ? s[t - o] : 0;
    __syncthreads();
    s[t] += u;
    __syncthreads();
  }
  if (t < NB) {
    bucket_base[t] = s[t] - v;
    cursor[t] = s[t] - v;
  }
  if (t == 255) {
    bucket_base[NB] = s[255];
    offs[N] = s[255];
  }
}

__global__ __launch_bounds__(256) void bin_kernel(const int* __restrict__ src,
                                                  const int* __restrict__ dst,
                                                  int* __restrict__ cursor,
                                                  unsigned int* __restrict__ binned,
                                                  int E, int NB) {
  __shared__ int lcount[256], lbase[256], lcur[256], lgbase[256], sscan[256];
  __shared__ unsigned int stage[BIN_CH];
  const int t = threadIdx.x;
  const int cb = blockIdx.x * BIN_CH;
  lcount[t] = 0;
  __syncthreads();

  int sv[BIN_CH / 256], dv[BIN_CH / 256];
#pragma unroll
  for (int i = 0; i < BIN_CH / 256; ++i) {
    const int idx = cb + i * 256 + t;
    if (idx < E) {
      sv[i] = src[idx];
      dv[i] = dst[idx];
      atomicAdd(&lcount[dv[i] >> 8], 1);
    } else {
      sv[i] = -1;
    }
  }
  __syncthreads();
  sscan[t] = lcount[t];
  __syncthreads();
#pragma unroll
  for (int o = 1; o < 256; o <<= 1) {
    int u = (t >= o) ? sscan[t - o] : 0;
    __syncthreads();
    sscan[t] += u;
    __syncthreads();
  }
  lbase[t] = sscan[t] - lcount[t];
  lcur[t] = lbase[t];
  __syncthreads();
#pragma unroll
  for (int i = 0; i < BIN_CH / 256; ++i) {
    if (sv[i] >= 0) {
      const int b = dv[i] >> 8;
      const int pos = atomicAdd(&lcur[b], 1);
      stage[pos] = (unsigned)sv[i] | ((unsigned)(dv[i] & 255) << 16) | ((unsigned)b << 24);
    }
  }
  __syncthreads();
  if (t < NB && lcount[t]) lgbase[t] = atomicAdd(&cursor[t], lcount[t]);
  __syncthreads();
  const int total = (cb + BIN_CH <= E) ? BIN_CH : (E - cb);
  for (int idx = t; idx < total; idx += 256) {
    const unsigned int rec = stage[idx];
    const int b = rec >> 24;
    binned[lgbase[b] + (idx - lbase[b])] = rec;
  }
}

__global__ __launch_bounds__(256) void build_kernel(const unsigned int* __restrict__ binned,
                                                    const int* __restrict__ bucket_base,
                                                    int* __restrict__ csr,
                                                    int* __restrict__ offs, int N) {
  __shared__ int ncount[256], ncur[256], sscan[256];
  const int b = blockIdx.x;
  const int t = threadIdx.x;
  const int nstart = b << 8;
  const int rb = bucket_base[b], re = bucket_base[b + 1];
  ncount[t] = 0;
  __syncthreads();
  for (int idx = rb + t; idx < re; idx += 256)
    atomicAdd(&ncount[(binned[idx] >> 16) & 255], 1);
  __syncthreads();
  sscan[t] = ncount[t];
  __syncthreads();
#pragma unroll
  for (int o = 1; o < 256; o <<= 1) {
    int u = (t >= o) ? sscan[t - o] : 0;
    __syncthreads();
    sscan[t] += u;
    __syncthreads();
  }
  const int excl = sscan[t] - ncount[t];
  ncur[t] = excl;
  if (nstart + t < N) offs[nstart + t] = rb + excl;
  __syncthreads();
  for (int idx = rb + t; idx < re; idx += 256) {
    const unsigned int rec = binned[idx];
    const int p = atomicAdd(&ncur[(rec >> 16) & 255], 1);
    csr[rb + p] = (int)(rec & 0xffffu);
  }
}

// ============ prep: f32 -> bf16 convert; weight fragment packing ============
__global__ __launch_bounds__(256) void cvt_x_kernel(const float* __restrict__ X,
                                                    unsigned int* __restrict__ Xb, int n4) {
  int i = blockIdx.x * 256 + threadIdx.x;
  if (i >= n4) return;
  float4 v = ((const float4*)X)[i];
  uint2 o;
  o.x = cvt_pk_bf16(v.x, v.y);
  o.y = cvt_pk_bf16(v.z, v.w);
  ((uint2*)Xb)[i] = o;
}

// pack W [nmats][128][128] f32 -> MFMA B-fragment order bf16 (K tiles = 4)
__global__ __launch_bounds__(256) void pack_w_kernel(const float* __restrict__ W,
                                                     unsigned short* __restrict__ P,
                                                     int nmats) {
  int q = blockIdx.x * 256 + threadIdx.x;
  if (q >= nmats * 16384) return;
  int mat = q >> 14;
  int r = q & 16383;
  int e = r & 7, l = (r >> 3) & 63, ks = (r >> 9) & 3, ct = r >> 11;
  int k = ks * 32 + (l >> 4) * 8 + e;
  int n = ct * 16 + (l & 15);
  P[q] = f2bf(W[(size_t)mat * 16384 + k * DD + n]);
}

// pack out_w [384][256] f32 -> B-fragment order bf16: P[((ct*12+ks)*64+l)*8+e]
__global__ __launch_bounds__(256) void pack_wo_kernel(const float* __restrict__ W,
                                                      unsigned short* __restrict__ P) {
  int q = blockIdx.x * 256 + threadIdx.x;
  if (q >= 384 * 256) return;
  int e = q & 7, l = (q >> 3) & 63;
  int rest = q >> 9;
  int ks = rest % 12, ct = rest / 12;
  int k = ks * 32 + (l >> 4) * 8 + e;
  int n = ct * 16 + (l & 15);
  P[q] = f2bf(W[(size_t)k * 256 + n]);
}

// ============ fused GIN layer: gather+sum -> relu(relu(z@W1)@W2) ============
__device__ __forceinline__ void bfacc8(float* a, uint4 v) {
  a[0] += __uint_as_float(v.x << 16);
  a[1] += __uint_as_float(v.x & 0xffff0000u);
  a[2] += __uint_as_float(v.y << 16);
  a[3] += __uint_as_float(v.y & 0xffff0000u);
  a[4] += __uint_as_float(v.z << 16);
  a[5] += __uint_as_float(v.z & 0xffff0000u);
  a[6] += __uint_as_float(v.w << 16);
  a[7] += __uint_as_float(v.w & 0xffff0000u);
}

// block = 256 threads (4 waves) handles 32 rows. Phase 1: each wave gathers
// 8 nodes (quarter-wave x uint4, 2 rows in flight, shfl-combine) into the
// swizzled LDS z-tile. Phase 2/3: block-cooperative double MFMA GEMM (wave w
// owns col-tiles {2w, 2w+1}); h1 routed through LDS in C/D layout. NOT
// in-place: reads H4 (prev layer), writes Hout (next buffer).
__global__ __launch_bounds__(256) void gin_layer_kernel(
    const uint4* __restrict__ H4, const int* __restrict__ offs,
    const int* __restrict__ csr_src,
    const unsigned short* __restrict__ W1p,
    const unsigned short* __restrict__ W2p,
    unsigned short* __restrict__ Hout, int N) {
  __shared__ unsigned short zl[32 * DD];  // 8 KB z tile (later reused for out)
  __shared__ unsigned short h1[32 * DD];  // 8 KB h1 tile
  const int t = threadIdx.x;
  const int w = t >> 6;
  const int l = t & 63;
  const int qw = l >> 4;
  const int ql = l & 15;
  const int row0 = blockIdx.x * 32;

  // ---- phase 1: gather + sum -> zl (swizzled 16B chunks) ----
#pragma unroll
  for (int i = 0; i < 8; ++i) {
    const int mrow = w * 8 + i;
    const int node = row0 + mrow;
    float acc[8] = {0.f, 0.f, 0.f, 0.f, 0.f, 0.f, 0.f, 0.f};
    if (node < N) {
      if (qw == 0) bfacc8(acc, H4[(size_t)node * 16 + ql]);
      const int e1 = offs[node + 1];
      int e = offs[node] + qw;
      for (; e + 4 < e1; e += 8) {
        uint4 a = H4[(size_t)csr_src[e] * 16 + ql];
        uint4 b = H4[(size_t)csr_src[e + 4] * 16 + ql];
        bfacc8(acc, a);
        bfacc8(acc, b);
      }
      if (e < e1) bfacc8(acc, H4[(size_t)csr_src[e] * 16 + ql]);
    }
#pragma unroll
    for (int j = 0; j < 8; ++j) {
      acc[j] += __shfl_xor(acc[j], 16, 64);
      acc[j] += __shfl_xor(acc[j], 32, 64);
    }
    if (qw == 0) {
      uint4 o;
      o.x = cvt_pk_bf16(acc[0], acc[1]);
      o.y = cvt_pk_bf16(acc[2], acc[3]);
      o.z = cvt_pk_bf16(acc[4], acc[5]);
      o.w = cvt_pk_bf16(acc[6], acc[7]);
      *(uint4*)&zl[mrow * DD + ((ql ^ (mrow & 7)) << 3)] = o;
    }
  }
  __syncthreads();

  const int m_a = l & 15;
  const int g = l >> 4;

  // ---- phase 2: GEMM1 (wave w: col-tiles 2w, 2w+1) ----
  f32x4 acc1[2][2];
#pragma unroll
  for (int t2 = 0; t2 < 2; ++t2)
#pragma unroll
    for (int j = 0; j < 2; ++j) acc1[t2][j] = (f32x4){0.f, 0.f, 0.f, 0.f};

#pragma unroll
  for (int ks = 0; ks < 4; ++ks) {
    const int c8 = ks * 4 + g;
    short8 a0 = *(const short8*)&zl[m_a * DD + ((c8 ^ (m_a & 7)) << 3)];
    short8 a1 = *(const short8*)&zl[(16 + m_a) * DD + ((c8 ^ (m_a & 7)) << 3)];
#pragma unroll
    for (int j = 0; j < 2; ++j) {
      const int ct = w * 2 + j;
      short8 b = *(const short8*)&W1p[(size_t)((ct * 4 + ks) * 64 + l) * 8];
      acc1[0][j] = __builtin_amdgcn_mfma_f32_16x16x32_bf16(a0, b, acc1[0][j], 0, 0, 0);
      acc1[1][j] = __builtin_amdgcn_mfma_f32_16x16x32_bf16(a1, b, acc1[1][j], 0, 0, 0);
    }
  }
  // relu -> h1 (C/D layout: col = ct*16 + m_a, row = t2*16 + g*4 + r)
#pragma unroll
  for (int t2 = 0; t2 < 2; ++t2)
#pragma unroll
    for (int j = 0; j < 2; ++j) {
      const int c = (w * 2 + j) * 16 + m_a;
#pragma unroll
      for (int r = 0; r < 4; r += 2) {
        unsigned int p = cvt_pk_bf16(fmaxf(acc1[t2][j][r], 0.f),
                                     fmaxf(acc1[t2][j][r + 1], 0.f));
        const int m0 = t2 * 16 + g * 4 + r;
        const int m1 = m0 + 1;
        h1[m0 * DD + (((c >> 3) ^ (m0 & 7)) << 3) + (c & 7)] = (unsigned short)p;
        h1[m1 * DD + (((c >> 3) ^ (m1 & 7)) << 3) + (c & 7)] = (unsigned short)(p >> 16);
      }
    }
  __syncthreads();

  // ---- phase 3: GEMM2; out (relu) -> zl (z fully consumed by all waves) ----
  f32x4 acc2[2][2];
#pragma unroll
  for (int t2 = 0; t2 < 2; ++t2)
#pragma unroll
    for (int j = 0; j < 2; ++j) acc2[t2][j] = (f32x4){0.f, 0.f, 0.f, 0.f};

#pragma unroll
  for (int ks = 0; ks < 4; ++ks) {
    const int c8 = ks * 4 + g;
    short8 a0 = *(const short8*)&h1[m_a * DD + ((c8 ^ (m_a & 7)) << 3)];
    short8 a1 = *(const short8*)&h1[(16 + m_a) * DD + ((c8 ^ (m_a & 7)) << 3)];
#pragma unroll
    for (int j = 0; j < 2; ++j) {
      const int ct = w * 2 + j;
      short8 b = *(const short8*)&W2p[(size_t)((ct * 4 + ks) * 64 + l) * 8];
      acc2[0][j] = __builtin_amdgcn_mfma_f32_16x16x32_bf16(a0, b, acc2[0][j], 0, 0, 0);
      acc2[1][j] = __builtin_amdgcn_mfma_f32_16x16x32_bf16(a1, b, acc2[1][j], 0, 0, 0);
    }
  }
#pragma unroll
  for (int t2 = 0; t2 < 2; ++t2)
#pragma unroll
    for (int j = 0; j < 2; ++j) {
      const int c = (w * 2 + j) * 16 + m_a;
#pragma unroll
      for (int r = 0; r < 4; r += 2) {
        unsigned int p = cvt_pk_bf16(fmaxf(acc2[t2][j][r], 0.f),
                                     fmaxf(acc2[t2][j][r + 1], 0.f));
        const int m0 = t2 * 16 + g * 4 + r;
        const int m1 = m0 + 1;
        zl[m0 * DD + (((c >> 3) ^ (m0 & 7)) << 3) + (c & 7)] = (unsigned short)p;
        zl[m1 * DD + (((c >> 3) ^ (m1 & 7)) << 3) + (c & 7)] = (unsigned short)(p >> 16);
      }
    }
  __syncthreads();

  // ---- store: block-wide coalesced (512 16B chunks, 2 per thread) ----
#pragma unroll
  for (int it = 0; it < 2; ++it) {
    const int q = t + it * 256;
    const int m = q >> 4;
    const int c8 = q & 15;
    short8 v = *(const short8*)&zl[m * DD + ((c8 ^ (m & 7)) << 3)];
    *(short8*)(Hout + (size_t)(row0 + m) * DD + c8 * 8) = v;
  }
}

// ============ pooled readout -> bf16 [G][384] rows: [gmax|gmean|gsum] ============
__device__ __forceinline__ int lower_bound_dev(const int* a, int n, int v) {
  int lo = 0, hi = n;
  while (lo < hi) {
    int mid = (lo + hi) >> 1;
    if (a[mid] < v) lo = mid + 1; else hi = mid;
  }
  return lo;
}

__global__ __launch_bounds__(256) void pool_kernel(const unsigned int* __restrict__ H2,
                                                   const int* __restrict__ batch,
                                                   unsigned int* __restrict__ pooled_bf,
                                                   int N) {
  const int g = blockIdx.x;
  __shared__ int sRange[2];
  if (threadIdx.x < 2) sRange[threadIdx.x] = lower_bound_dev(batch, N, g + threadIdx.x);
  __syncthreads();
  const int lo = sRange[0], hi = sRange[1];
  const int cp = threadIdx.x & 63;
  const int sl = threadIdx.x >> 6;
  float sx = 0.f, sy = 0.f, mx = 0.f, my = 0.f;
  for (int r = lo + sl; r < hi; r += 4) {
    unsigned int u = H2[(size_t)r * 64 + cp];
    float a = __uint_as_float(u << 16);
    float b = __uint_as_float(u & 0xffff0000u);
    sx += a; sy += b;
    mx = fmaxf(mx, a); my = fmaxf(my, b);
  }
  __shared__ float sS[3][DD], sM[3][DD];
  if (sl > 0) {
    sS[sl - 1][cp * 2] = sx; sS[sl - 1][cp * 2 + 1] = sy;
    sM[sl - 1][cp * 2] = mx; sM[sl - 1][cp * 2 + 1] = my;
  }
  __syncthreads();
  if (sl == 0) {
#pragma unroll
    for (int j = 0; j < 3; ++j) {
      sx += sS[j][cp * 2]; sy += sS[j][cp * 2 + 1];
      mx = fmaxf(mx, sM[j][cp * 2]); my = fmaxf(my, sM[j][cp * 2 + 1]);
    }
    const float cnt = fmaxf((float)(hi - lo), 1.f);
    const size_t pb = (size_t)g * 192;  // 384 bf16 = 192 uints
    pooled_bf[pb + cp] = cvt_pk_bf16(mx, my);
    pooled_bf[pb + 64 + cp] = cvt_pk_bf16(sx / cnt, sy / cnt);
    pooled_bf[pb + 128 + cp] = cvt_pk_bf16(sx, sy);
  }
}

// ============ final MFMA GEMM: out[G,256] = pooled[G,384] @ out_w + bo ============
__global__ __launch_bounds__(256) void final_mfma_kernel(const unsigned short* __restrict__ Pb,
                                                         const unsigned short* __restrict__ Wop,
                                                         const float* __restrict__ bo,
                                                         float* __restrict__ out, int G) {
  const int w = threadIdx.x >> 6;
  const int l = threadIdx.x & 63;
  const int rt = blockIdx.x >> 2;
  const int cg = blockIdx.x & 3;
  const int ct = cg * 4 + w;
  const int row0 = rt * 16;
  const int m_a = l & 15;
  const int g = l >> 4;

  f32x4 acc = (f32x4){0.f, 0.f, 0.f, 0.f};
#pragma unroll
  for (int ks = 0; ks < 12; ++ks) {
    short8 a = *(const short8*)&Pb[((size_t)(row0 + m_a) * 384) + ks * 32 + g * 8];
    short8 b = *(const short8*)&Wop[(size_t)((ct * 12 + ks) * 64 + l) * 8];
    acc = __builtin_amdgcn_mfma_f32_16x16x32_bf16(a, b, acc, 0, 0, 0);
  }

  const int n = ct * 16 + m_a;
  const float bias = bo[n];
#pragma unroll
  for (int r = 0; r < 4; ++r) {
    const int row = row0 + g * 4 + r;
    if (row < G) out[(size_t)row * 256 + n] = acc[r] + bias;
  }
}

// ======================= launch =======================
extern "C" void kernel_launch(void* const* d_in, const int* in_sizes, int n_in,
                              void* d_out, int out_size, void* d_ws, size_t ws_size,
                              hipStream_t stream) {
  const float* x     = (const float*)d_in[0];
  const int*   ei    = (const int*)d_in[1];
  const int*   batch = (const int*)d_in[2];
  const float* w1_0  = (const float*)d_in[3];
  const float* w2_0  = (const float*)d_in[4];
  const float* gw1   = (const float*)d_in[5];
  const float* gw2   = (const float*)d_in[6];
  const float* out_w = (const float*)d_in[7];
  const float* out_b = (const float*)d_in[8];

  const int N   = in_sizes[0] / DD;        // 50000 (fits 16-bit src pack)
  const int E   = in_sizes[1] / 2;
  const int Lm1 = in_sizes[5] / (DD * DD);
  const int OUT = in_sizes[7] / (3 * DD);  // 256
  const int G   = out_size / OUT;          // 256

  const int* src = ei;
  const int* dst = ei + E;
  const int NB = (N + 255) >> 8;
  const int nmats = 2 + 2 * Lm1;
  const int Npad = (N + 31) & ~31;
  const int Gpad = (G + 15) & ~15;

  char* p = (char*)d_ws;
  auto take = [&](size_t bytes) -> char* {
    char* r = p;
    p += (bytes + 511) & ~(size_t)511;
    return r;
  };
  int* cnt         = (int*)take((size_t)NB * 4);
  int* bucket_base = (int*)take((size_t)(NB + 1) * 4);
  int* cursor      = (int*)take((size_t)NB * 4);
  unsigned int* binned = (unsigned int*)take((size_t)E * 4);
  int* csr         = (int*)take((size_t)E * 4);
  int* offs        = (int*)take((size_t)(N + 1) * 4);
  unsigned short* packW = (unsigned short*)take((size_t)nmats * 16384 * 2);
  unsigned short* packWo = (unsigned short*)take((size_t)384 * 256 * 2);
  unsigned short* xb    = (unsigned short*)take((size_t)Npad * DD * 2);
  unsigned short* bufA  = (unsigned short*)take((size_t)Npad * DD * 2);
  unsigned short* bufB  = (unsigned short*)take((size_t)Npad * DD * 2);
  unsigned int* pooled_bf = (unsigned int*)take((size_t)Gpad * 192 * 4);

  // ---- prep: weight packing + x conversion ----
  pack_w_kernel<<<(1 * 16384 + 255) / 256, 256, 0, stream>>>(w1_0, packW, 1);
  pack_w_kernel<<<(1 * 16384 + 255) / 256, 256, 0, stream>>>(w2_0, packW + 16384, 1);
  pack_w_kernel<<<(Lm1 * 16384 + 255) / 256, 256, 0, stream>>>(gw1, packW + 2 * 16384, Lm1);
  pack_w_kernel<<<(Lm1 * 16384 + 255) / 256, 256, 0, stream>>>(gw2, packW + (size_t)(2 + Lm1) * 16384, Lm1);
  pack_wo_kernel<<<(384 * 256 + 255) / 256, 256, 0, stream>>>(out_w, packWo);
  cvt_x_kernel<<<(N * DD / 4 + 255) / 256, 256, 0, stream>>>(x, (unsigned int*)xb, N * DD / 4);

  // ---- CSR build (bucketed) ----
  hipMemsetAsync(cnt, 0, (size_t)NB * 4, stream);
  bhist_kernel<<<196, 256, 0, stream>>>(dst, cnt, E, NB);
  bscan_kernel<<<1, 256, 0, stream>>>(cnt, bucket_base, cursor, offs, NB, N);
  bin_kernel<<<(E + BIN_CH - 1) / BIN_CH, 256, 0, stream>>>(src, dst, cursor, binned, E, NB);
  build_kernel<<<NB, 256, 0, stream>>>(binned, bucket_base, csr, offs, N);

  // ---- 3 fused GIN layers (gather + MLP in one kernel; ping-pong buffers) ----
  const int ntiles32 = Npad / 32;
  const unsigned short* hcur = xb;
  unsigned short* bufs[2] = {bufA, bufB};
  for (int l = 0; l <= Lm1; ++l) {
    unsigned short* hout = bufs[l & 1];
    const unsigned short* W1p = packW + (size_t)((l == 0) ? 0 : (2 + (l - 1))) * 16384;
    const unsigned short* W2p = packW + (size_t)((l == 0) ? 1 : (2 + Lm1 + (l - 1))) * 16384;
    gin_layer_kernel<<<ntiles32, 256, 0, stream>>>(
        (const uint4*)hcur, offs, csr, W1p, W2p, hout, N);
    hcur = hout;
  }

  // ---- readout ----
  pool_kernel<<<G, 256, 0, stream>>>((const unsigned int*)hcur, batch, pooled_bf, N);
  final_mfma_kernel<<<(Gpad / 16) * 4, 256, 0, stream>>>(
      (const unsigned short*)pooled_bf, packWo, out_b, (float*)d_out, G);
}

// Round 9
// 166.185 us; speedup vs baseline: 1.6660x; 1.1493x over previous
//
#include <hip/hip_runtime.h>

#define DD 128
#define BIN_CH 2048  // edges staged per bin block

typedef __attribute__((ext_vector_type(8))) short short8;
typedef __attribute__((ext_vector_type(4))) float f32x4;

__device__ __forceinline__ unsigned short f2bf(float x) {
  unsigned int b = __float_as_uint(x);
  b += 0x7fffu + ((b >> 16) & 1u);
  return (unsigned short)(b >> 16);
}

__device__ __forceinline__ unsigned int cvt_pk_bf16(float lo, float hi) {
  unsigned int d;
  asm("v_cvt_pk_bf16_f32 %0, %1, %2" : "=v"(d) : "v"(lo), "v"(hi));
  return d;
}

// ============== CSR build, bucketed (bucket = dst >> 8, <=256 buckets) ==============
__global__ __launch_bounds__(256) void bhist_kernel(const int* __restrict__ dst,
                                                    int* __restrict__ cnt, int E, int NB) {
  __shared__ int lh[256];
  const int t = threadIdx.x;
  lh[t] = 0;
  __syncthreads();
  const int e4 = E >> 2;
  const int4* d4 = (const int4*)dst;
  for (int i = blockIdx.x * 256 + t; i < e4; i += gridDim.x * 256) {
    int4 v = d4[i];
    atomicAdd(&lh[v.x >> 8], 1);
    atomicAdd(&lh[v.y >> 8], 1);
    atomicAdd(&lh[v.z >> 8], 1);
    atomicAdd(&lh[v.w >> 8], 1);
  }
  if (blockIdx.x == 0) {
    for (int i = (e4 << 2) + t; i < E; i += 256) atomicAdd(&lh[dst[i] >> 8], 1);
  }
  __syncthreads();
  if (t < NB && lh[t]) atomicAdd(&cnt[t], lh[t]);
}

__global__ __launch_bounds__(256) void bscan_kernel(const int* __restrict__ cnt,
                                                    int* __restrict__ bucket_base,
                                                    int* __restrict__ cursor,
                                                    int* __restrict__ offs, int NB, int N) {
  __shared__ int s[256];
  const int t = threadIdx.x;
  int v = (t < NB) ? cnt[t] : 0;
  s[t] = v;
  __syncthreads();
#pragma unroll
  for (int o = 1; o < 256; o <<= 1) {
    int u = (t >= o) ? s[t - o] : 0;
    __syncthreads();
    s[t] += u;
    __syncthreads();
  }
  if (t < NB) {
    bucket_base[t] = s[t] - v;
    cursor[t] = s[t] - v;
  }
  if (t == 255) {
    bucket_base[NB] = s[255];
    offs[N] = s[255];
  }
}

__global__ __launch_bounds__(256) void bin_kernel(const int* __restrict__ src,
                                                  const int* __restrict__ dst,
                                                  int* __restrict__ cursor,
                                                  unsigned int* __restrict__ binned,
                                                  int E, int NB) {
  __shared__ int lcount[256], lbase[256], lcur[256], lgbase[256], sscan[256];
  __shared__ unsigned int stage[BIN_CH];
  const int t = threadIdx.x;
  const int cb = blockIdx.x * BIN_CH;
  lcount[t] = 0;
  __syncthreads();

  int sv[BIN_CH / 256], dv[BIN_CH / 256];
#pragma unroll
  for (int i = 0; i < BIN_CH / 256; ++i) {
    const int idx = cb + i * 256 + t;
    if (idx < E) {
      sv[i] = src[idx];
      dv[i] = dst[idx];
      atomicAdd(&lcount[dv[i] >> 8], 1);
    } else {
      sv[i] = -1;
    }
  }
  __syncthreads();
  sscan[t] = lcount[t];
  __syncthreads();
#pragma unroll
  for (int o = 1; o < 256; o <<= 1) {
    int u = (t >= o) ? sscan[t - o] : 0;
    __syncthreads();
    sscan[t] += u;
    __syncthreads();
  }
  lbase[t] = sscan[t] - lcount[t];
  lcur[t] = lbase[t];
  __syncthreads();
#pragma unroll
  for (int i = 0; i < BIN_CH / 256; ++i) {
    if (sv[i] >= 0) {
      const int b = dv[i] >> 8;
      const int pos = atomicAdd(&lcur[b], 1);
      stage[pos] = (unsigned)sv[i] | ((unsigned)(dv[i] & 255) << 16) | ((unsigned)b << 24);
    }
  }
  __syncthreads();
  if (t < NB && lcount[t]) lgbase[t] = atomicAdd(&cursor[t], lcount[t]);
  __syncthreads();
  const int total = (cb + BIN_CH <= E) ? BIN_CH : (E - cb);
  for (int idx = t; idx < total; idx += 256) {
    const unsigned int rec = stage[idx];
    const int b = rec >> 24;
    binned[lgbase[b] + (idx - lbase[b])] = rec;
  }
}

// build: one block per bucket; csr entries stored as ushort (src < 65536)
__global__ __launch_bounds__(256) void build_kernel(const unsigned int* __restrict__ binned,
                                                    const int* __restrict__ bucket_base,
                                                    unsigned short* __restrict__ csr16,
                                                    int* __restrict__ offs, int N) {
  __shared__ int ncount[256], ncur[256], sscan[256];
  const int b = blockIdx.x;
  const int t = threadIdx.x;
  const int nstart = b << 8;
  const int rb = bucket_base[b], re = bucket_base[b + 1];
  ncount[t] = 0;
  __syncthreads();
  for (int idx = rb + t; idx < re; idx += 256)
    atomicAdd(&ncount[(binned[idx] >> 16) & 255], 1);
  __syncthreads();
  sscan[t] = ncount[t];
  __syncthreads();
#pragma unroll
  for (int o = 1; o < 256; o <<= 1) {
    int u = (t >= o) ? sscan[t - o] : 0;
    __syncthreads();
    sscan[t] += u;
    __syncthreads();
  }
  const int excl = sscan[t] - ncount[t];
  ncur[t] = excl;
  if (nstart + t < N) offs[nstart + t] = rb + excl;
  __syncthreads();
  for (int idx = rb + t; idx < re; idx += 256) {
    const unsigned int rec = binned[idx];
    const int p = atomicAdd(&ncur[(rec >> 16) & 255], 1);
    csr16[rb + p] = (unsigned short)(rec & 0xffffu);
  }
}

// ============ fused prep: cvt_x | pack W1/W2/gw1/gw2 | pack out_w | zero cnt ============
__global__ __launch_bounds__(256) void prep_kernel(
    const float* __restrict__ x, const float* __restrict__ w1_0,
    const float* __restrict__ w2_0, const float* __restrict__ gw1,
    const float* __restrict__ gw2, const float* __restrict__ out_w,
    unsigned int* __restrict__ xb, unsigned short* __restrict__ packW,
    unsigned short* __restrict__ packWo, int* __restrict__ cnt,
    int n4, int nmats, int Lm1, int NB) {
  int q = blockIdx.x * 256 + threadIdx.x;
  if (q < n4) {  // x f32 -> bf16, vectorized
    float4 v = ((const float4*)x)[q];
    uint2 o;
    o.x = cvt_pk_bf16(v.x, v.y);
    o.y = cvt_pk_bf16(v.z, v.w);
    ((uint2*)xb)[q] = o;
    return;
  }
  q -= n4;
  const int npack = nmats * 16384;
  if (q < npack) {  // square weights -> B-fragment order
    const int mat = q >> 14;
    const float* W;
    if (mat == 0) W = w1_0;
    else if (mat == 1) W = w2_0;
    else if (mat < 2 + Lm1) W = gw1 + (size_t)(mat - 2) * 16384;
    else W = gw2 + (size_t)(mat - 2 - Lm1) * 16384;
    const int r = q & 16383;
    const int e = r & 7, l = (r >> 3) & 63, ks = (r >> 9) & 3, ct = r >> 11;
    const int k = ks * 32 + (l >> 4) * 8 + e;
    const int n = ct * 16 + (l & 15);
    packW[q] = f2bf(W[(size_t)k * DD + n]);
    return;
  }
  q -= npack;
  if (q < 384 * 256) {  // out_w [384][256] -> B-fragment order (12 k-slices)
    const int e = q & 7, l = (q >> 3) & 63;
    const int rest = q >> 9;
    const int ks = rest % 12, ct = rest / 12;
    const int k = ks * 32 + (l >> 4) * 8 + e;
    const int n = ct * 16 + (l & 15);
    packWo[q] = f2bf(out_w[(size_t)k * 256 + n]);
    return;
  }
  q -= 384 * 256;
  if (q < NB) cnt[q] = 0;  // replaces the memset dispatch
}

// ============ fused GIN layer: gather+sum -> relu(relu(z@W1)@W2) ============
__device__ __forceinline__ void bfacc8(float* a, uint4 v) {
  a[0] += __uint_as_float(v.x << 16);
  a[1] += __uint_as_float(v.x & 0xffff0000u);
  a[2] += __uint_as_float(v.y << 16);
  a[3] += __uint_as_float(v.y & 0xffff0000u);
  a[4] += __uint_as_float(v.z << 16);
  a[5] += __uint_as_float(v.z & 0xffff0000u);
  a[6] += __uint_as_float(v.w << 16);
  a[7] += __uint_as_float(v.w & 0xffff0000u);
}

// block = 256 threads (4 waves) handles 32 rows. Phase 1: each QUARTER-WAVE
// owns one node at a time (16 lanes x uint4 = full 256B row), walking its
// edge list with a 4-deep unrolled loop -> 16 independent gather streams per
// block, no shuffles. Phase 2/3: block-cooperative double MFMA GEMM.
__global__ __launch_bounds__(256) void gin_layer_kernel(
    const uint4* __restrict__ H4, const int* __restrict__ offs,
    const unsigned short* __restrict__ csr16,
    const unsigned short* __restrict__ W1p,
    const unsigned short* __restrict__ W2p,
    unsigned short* __restrict__ Hout, int N) {
  __shared__ unsigned short zl[32 * DD];  // 8 KB z tile (later reused for out)
  __shared__ unsigned short h1[32 * DD];  // 8 KB h1 tile
  const int t = threadIdx.x;
  const int quarter = t >> 4;  // 0..15
  const int ql = t & 15;       // lane covers bf16 cols [ql*8, ql*8+8)
  const int row0 = blockIdx.x * 32;

  // ---- phase 1: gather + sum; quarter q handles rows q and q+16 ----
#pragma unroll
  for (int i = 0; i < 2; ++i) {
    const int mrow = quarter + i * 16;
    const int node = row0 + mrow;
    float acc[8] = {0.f, 0.f, 0.f, 0.f, 0.f, 0.f, 0.f, 0.f};
    if (node < N) {
      bfacc8(acc, H4[(size_t)node * 16 + ql]);  // self
      const int e1 = offs[node + 1];
      int e = offs[node];
      for (; e + 3 < e1; e += 4) {  // 4 rows (64B/lane) in flight
        uint4 a = H4[(size_t)csr16[e] * 16 + ql];
        uint4 b = H4[(size_t)csr16[e + 1] * 16 + ql];
        uint4 c = H4[(size_t)csr16[e + 2] * 16 + ql];
        uint4 d = H4[(size_t)csr16[e + 3] * 16 + ql];
        bfacc8(acc, a);
        bfacc8(acc, b);
        bfacc8(acc, c);
        bfacc8(acc, d);
      }
      for (; e < e1; ++e) bfacc8(acc, H4[(size_t)csr16[e] * 16 + ql]);
    }
    uint4 o;
    o.x = cvt_pk_bf16(acc[0], acc[1]);
    o.y = cvt_pk_bf16(acc[2], acc[3]);
    o.z = cvt_pk_bf16(acc[4], acc[5]);
    o.w = cvt_pk_bf16(acc[6], acc[7]);
    *(uint4*)&zl[mrow * DD + ((ql ^ (mrow & 7)) << 3)] = o;
  }
  __syncthreads();

  const int w = t >> 6;
  const int l = t & 63;
  const int m_a = l & 15;
  const int g = l >> 4;

  // ---- phase 2: GEMM1 (wave w: col-tiles 2w, 2w+1) ----
  f32x4 acc1[2][2];
#pragma unroll
  for (int t2 = 0; t2 < 2; ++t2)
#pragma unroll
    for (int j = 0; j < 2; ++j) acc1[t2][j] = (f32x4){0.f, 0.f, 0.f, 0.f};

#pragma unroll
  for (int ks = 0; ks < 4; ++ks) {
    const int c8 = ks * 4 + g;
    short8 a0 = *(const short8*)&zl[m_a * DD + ((c8 ^ (m_a & 7)) << 3)];
    short8 a1 = *(const short8*)&zl[(16 + m_a) * DD + ((c8 ^ (m_a & 7)) << 3)];
#pragma unroll
    for (int j = 0; j < 2; ++j) {
      const int ct = w * 2 + j;
      short8 b = *(const short8*)&W1p[(size_t)((ct * 4 + ks) * 64 + l) * 8];
      acc1[0][j] = __builtin_amdgcn_mfma_f32_16x16x32_bf16(a0, b, acc1[0][j], 0, 0, 0);
      acc1[1][j] = __builtin_amdgcn_mfma_f32_16x16x32_bf16(a1, b, acc1[1][j], 0, 0, 0);
    }
  }
  // relu -> h1 (C/D layout: col = ct*16 + m_a, row = t2*16 + g*4 + r)
#pragma unroll
  for (int t2 = 0; t2 < 2; ++t2)
#pragma unroll
    for (int j = 0; j < 2; ++j) {
      const int c = (w * 2 + j) * 16 + m_a;
#pragma unroll
      for (int r = 0; r < 4; r += 2) {
        unsigned int p = cvt_pk_bf16(fmaxf(acc1[t2][j][r], 0.f),
                                     fmaxf(acc1[t2][j][r + 1], 0.f));
        const int m0 = t2 * 16 + g * 4 + r;
        const int m1 = m0 + 1;
        h1[m0 * DD + (((c >> 3) ^ (m0 & 7)) << 3) + (c & 7)] = (unsigned short)p;
        h1[m1 * DD + (((c >> 3) ^ (m1 & 7)) << 3) + (c & 7)] = (unsigned short)(p >> 16);
      }
    }
  __syncthreads();

  // ---- phase 3: GEMM2; out (relu) -> zl ----
  f32x4 acc2[2][2];
#pragma unroll
  for (int t2 = 0; t2 < 2; ++t2)
#pragma unroll
    for (int j = 0; j < 2; ++j) acc2[t2][j] = (f32x4){0.f, 0.f, 0.f, 0.f};

#pragma unroll
  for (int ks = 0; ks < 4; ++ks) {
    const int c8 = ks * 4 + g;
    short8 a0 = *(const short8*)&h1[m_a * DD + ((c8 ^ (m_a & 7)) << 3)];
    short8 a1 = *(const short8*)&h1[(16 + m_a) * DD + ((c8 ^ (m_a & 7)) << 3)];
#pragma unroll
    for (int j = 0; j < 2; ++j) {
      const int ct = w * 2 + j;
      short8 b = *(const short8*)&W2p[(size_t)((ct * 4 + ks) * 64 + l) * 8];
      acc2[0][j] = __builtin_amdgcn_mfma_f32_16x16x32_bf16(a0, b, acc2[0][j], 0, 0, 0);
      acc2[1][j] = __builtin_amdgcn_mfma_f32_16x16x32_bf16(a1, b, acc2[1][j], 0, 0, 0);
    }
  }
#pragma unroll
  for (int t2 = 0; t2 < 2; ++t2)
#pragma unroll
    for (int j = 0; j < 2; ++j) {
      const int c = (w * 2 + j) * 16 + m_a;
#pragma unroll
      for (int r = 0; r < 4; r += 2) {
        unsigned int p = cvt_pk_bf16(fmaxf(acc2[t2][j][r], 0.f),
                                     fmaxf(acc2[t2][j][r + 1], 0.f));
        const int m0 = t2 * 16 + g * 4 + r;
        const int m1 = m0 + 1;
        zl[m0 * DD + (((c >> 3) ^ (m0 & 7)) << 3) + (c & 7)] = (unsigned short)p;
        zl[m1 * DD + (((c >> 3) ^ (m1 & 7)) << 3) + (c & 7)] = (unsigned short)(p >> 16);
      }
    }
  __syncthreads();

  // ---- store: block-wide coalesced (512 16B chunks, 2 per thread) ----
#pragma unroll
  for (int it = 0; it < 2; ++it) {
    const int q = t + it * 256;
    const int m = q >> 4;
    const int c8 = q & 15;
    short8 v = *(const short8*)&zl[m * DD + ((c8 ^ (m & 7)) << 3)];
    *(short8*)(Hout + (size_t)(row0 + m) * DD + c8 * 8) = v;
  }
}

// ============ pooled readout -> bf16 [G][384] rows: [gmax|gmean|gsum] ============
__device__ __forceinline__ int lower_bound_dev(const int* a, int n, int v) {
  int lo = 0, hi = n;
  while (lo < hi) {
    int mid = (lo + hi) >> 1;
    if (a[mid] < v) lo = mid + 1; else hi = mid;
  }
  return lo;
}

__global__ __launch_bounds__(256) void pool_kernel(const unsigned int* __restrict__ H2,
                                                   const int* __restrict__ batch,
                                                   unsigned int* __restrict__ pooled_bf,
                                                   int N) {
  const int g = blockIdx.x;
  __shared__ int sRange[2];
  if (threadIdx.x < 2) sRange[threadIdx.x] = lower_bound_dev(batch, N, g + threadIdx.x);
  __syncthreads();
  const int lo = sRange[0], hi = sRange[1];
  const int cp = threadIdx.x & 63;
  const int sl = threadIdx.x >> 6;
  float sx = 0.f, sy = 0.f, mx = 0.f, my = 0.f;
  for (int r = lo + sl; r < hi; r += 4) {
    unsigned int u = H2[(size_t)r * 64 + cp];
    float a = __uint_as_float(u << 16);
    float b = __uint_as_float(u & 0xffff0000u);
    sx += a; sy += b;
    mx = fmaxf(mx, a); my = fmaxf(my, b);
  }
  __shared__ float sS[3][DD], sM[3][DD];
  if (sl > 0) {
    sS[sl - 1][cp * 2] = sx; sS[sl - 1][cp * 2 + 1] = sy;
    sM[sl - 1][cp * 2] = mx; sM[sl - 1][cp * 2 + 1] = my;
  }
  __syncthreads();
  if (sl == 0) {
#pragma unroll
    for (int j = 0; j < 3; ++j) {
      sx += sS[j][cp * 2]; sy += sS[j][cp * 2 + 1];
      mx = fmaxf(mx, sM[j][cp * 2]); my = fmaxf(my, sM[j][cp * 2 + 1]);
    }
    const float cnt = fmaxf((float)(hi - lo), 1.f);
    const size_t pb = (size_t)g * 192;  // 384 bf16 = 192 uints
    pooled_bf[pb + cp] = cvt_pk_bf16(mx, my);
    pooled_bf[pb + 64 + cp] = cvt_pk_bf16(sx / cnt, sy / cnt);
    pooled_bf[pb + 128 + cp] = cvt_pk_bf16(sx, sy);
  }
}

// ============ final MFMA GEMM: out[G,256] = pooled[G,384] @ out_w + bo ============
__global__ __launch_bounds__(256) void final_mfma_kernel(const unsigned short* __restrict__ Pb,
                                                         const unsigned short* __restrict__ Wop,
                                                         const float* __restrict__ bo,
                                                         float* __restrict__ out, int G) {
  const int w = threadIdx.x >> 6;
  const int l = threadIdx.x & 63;
  const int rt = blockIdx.x >> 2;
  const int cg = blockIdx.x & 3;
  const int ct = cg * 4 + w;
  const int row0 = rt * 16;
  const int m_a = l & 15;
  const int g = l >> 4;

  f32x4 acc = (f32x4){0.f, 0.f, 0.f, 0.f};
#pragma unroll
  for (int ks = 0; ks < 12; ++ks) {
    short8 a = *(const short8*)&Pb[((size_t)(row0 + m_a) * 384) + ks * 32 + g * 8];
    short8 b = *(const short8*)&Wop[(size_t)((ct * 12 + ks) * 64 + l) * 8];
    acc = __builtin_amdgcn_mfma_f32_16x16x32_bf16(a, b, acc, 0, 0, 0);
  }

  const int n = ct * 16 + m_a;
  const float bias = bo[n];
#pragma unroll
  for (int r = 0; r < 4; ++r) {
    const int row = row0 + g * 4 + r;
    if (row < G) out[(size_t)row * 256 + n] = acc[r] + bias;
  }
}

// ======================= launch =======================
extern "C" void kernel_launch(void* const* d_in, const int* in_sizes, int n_in,
                              void* d_out, int out_size, void* d_ws, size_t ws_size,
                              hipStream_t stream) {
  const float* x     = (const float*)d_in[0];
  const int*   ei    = (const int*)d_in[1];
  const int*   batch = (const int*)d_in[2];
  const float* w1_0  = (const float*)d_in[3];
  const float* w2_0  = (const float*)d_in[4];
  const float* gw1   = (const float*)d_in[5];
  const float* gw2   = (const float*)d_in[6];
  const float* out_w = (const float*)d_in[7];
  const float* out_b = (const float*)d_in[8];

  const int N   = in_sizes[0] / DD;        // 50000 (fits 16-bit src pack)
  const int E   = in_sizes[1] / 2;
  const int Lm1 = in_sizes[5] / (DD * DD);
  const int OUT = in_sizes[7] / (3 * DD);  // 256
  const int G   = out_size / OUT;          // 256

  const int* src = ei;
  const int* dst = ei + E;
  const int NB = (N + 255) >> 8;
  const int nmats = 2 + 2 * Lm1;
  const int Npad = (N + 31) & ~31;
  const int Gpad = (G + 15) & ~15;

  char* p = (char*)d_ws;
  auto take = [&](size_t bytes) -> char* {
    char* r = p;
    p += (bytes + 511) & ~(size_t)511;
    return r;
  };
  int* cnt         = (int*)take((size_t)NB * 4);
  int* bucket_base = (int*)take((size_t)(NB + 1) * 4);
  int* cursor      = (int*)take((size_t)NB * 4);
  unsigned int* binned = (unsigned int*)take((size_t)E * 4);
  unsigned short* csr16 = (unsigned short*)take((size_t)E * 2);
  int* offs        = (int*)take((size_t)(N + 1) * 4);
  unsigned short* packW = (unsigned short*)take((size_t)nmats * 16384 * 2);
  unsigned short* packWo = (unsigned short*)take((size_t)384 * 256 * 2);
  unsigned short* xb    = (unsigned short*)take((size_t)Npad * DD * 2);
  unsigned short* bufA  = (unsigned short*)take((size_t)Npad * DD * 2);
  unsigned short* bufB  = (unsigned short*)take((size_t)Npad * DD * 2);
  unsigned int* pooled_bf = (unsigned int*)take((size_t)Gpad * 192 * 4);

  // ---- fused prep (x-convert + all weight packs + cnt zero): 1 dispatch ----
  const int n4 = N * DD / 4;
  const int prep_total = n4 + nmats * 16384 + 384 * 256 + NB;
  prep_kernel<<<(prep_total + 255) / 256, 256, 0, stream>>>(
      x, w1_0, w2_0, gw1, gw2, out_w, (unsigned int*)xb, packW, packWo, cnt,
      n4, nmats, Lm1, NB);

  // ---- CSR build (bucketed) ----
  bhist_kernel<<<196, 256, 0, stream>>>(dst, cnt, E, NB);
  bscan_kernel<<<1, 256, 0, stream>>>(cnt, bucket_base, cursor, offs, NB, N);
  bin_kernel<<<(E + BIN_CH - 1) / BIN_CH, 256, 0, stream>>>(src, dst, cursor, binned, E, NB);
  build_kernel<<<NB, 256, 0, stream>>>(binned, bucket_base, csr16, offs, N);

  // ---- 3 fused GIN layers (gather + MLP in one kernel; ping-pong buffers) ----
  const int ntiles32 = Npad / 32;
  const unsigned short* hcur = xb;
  unsigned short* bufs[2] = {bufA, bufB};
  for (int l = 0; l <= Lm1; ++l) {
    unsigned short* hout = bufs[l & 1];
    const unsigned short* W1p = packW + (size_t)((l == 0) ? 0 : (2 + (l - 1))) * 16384;
    const unsigned short* W2p = packW + (size_t)((l == 0) ? 1 : (2 + Lm1 + (l - 1))) * 16384;
    gin_layer_kernel<<<ntiles32, 256, 0, stream>>>(
        (const uint4*)hcur, offs, csr16, W1p, W2p, hout, N);
    hcur = hout;
  }

  // ---- readout ----
  pool_kernel<<<G, 256, 0, stream>>>((const unsigned int*)hcur, batch, pooled_bf, N);
  final_mfma_kernel<<<(Gpad / 16) * 4, 256, 0, stream>>>(
      (const unsigned short*)pooled_bf, packWo, out_b, (float*)d_out, G);
}